// Round 4
// baseline (224.451 us; speedup 1.0000x reference)
//
#include <hip/hip_runtime.h>
#include <hip/hip_bf16.h>

#define SEQ 8192
#define HD 128
#define BM 128
#define BN 64
#define NQT (SEQ / BM)   // 64
#define THREADS 512
#define KTP 130          // kt pitch: 65 words == 1 mod 32 -> conflict-free
#define VTP 66           // vt pitch: 33 words == 1 mod 32
#define KT_BYTES (2 * BN * KTP * 2)        // 33280
#define SMEM_BYTES (KT_BYTES + 2 * HD * VTP * 2)  // 67072

typedef __bf16 bf16_t;
typedef __bf16 bf16x2 __attribute__((ext_vector_type(2)));
typedef __bf16 bf16x8 __attribute__((ext_vector_type(8)));
typedef float f32x4 __attribute__((ext_vector_type(4)));
typedef float f32x16 __attribute__((ext_vector_type(16)));
typedef unsigned int u32x4 __attribute__((ext_vector_type(4)));

#if __has_builtin(__builtin_amdgcn_exp2f)
__device__ inline float exp2_fast(float x) { return __builtin_amdgcn_exp2f(x); }
#else
__device__ inline float exp2_fast(float x) { return exp2f(x); }
#endif

// ---------------- prep: K -> bf16 row-major, V -> bf16 transposed ----------------
__global__ __launch_bounds__(256) void prep_kernel(const float* __restrict__ K,
                                                   const float* __restrict__ V,
                                                   bf16_t* __restrict__ Kb,
                                                   bf16_t* __restrict__ VT) {
  const int b = (int)blockIdx.x;
  const int tid = (int)threadIdx.x;
  if (b < 256) {
    // V^T tile: 64 (s) x 64 (d)
    __shared__ float tile[64][65];
    const int s0 = (b & 127) * 64;
    const int d0 = (b >> 7) * 64;
    const int r = tid >> 2;          // 0..63
    const int c0 = (tid & 3) * 16;   // 0,16,32,48
#pragma unroll
    for (int j4 = 0; j4 < 4; ++j4) {
      float4 x = *(const float4*)&V[(size_t)(s0 + r) * HD + d0 + c0 + j4 * 4];
      tile[r][c0 + j4 * 4 + 0] = x.x;
      tile[r][c0 + j4 * 4 + 1] = x.y;
      tile[r][c0 + j4 * 4 + 2] = x.z;
      tile[r][c0 + j4 * 4 + 3] = x.w;
    }
    __syncthreads();
    bf16x8 w0, w1;
#pragma unroll
    for (int j = 0; j < 8; ++j) w0[j] = (bf16_t)tile[c0 + j][r];
#pragma unroll
    for (int j = 0; j < 8; ++j) w1[j] = (bf16_t)tile[c0 + 8 + j][r];
    *(bf16x8*)&VT[(size_t)(d0 + r) * SEQ + s0 + c0] = w0;
    *(bf16x8*)&VT[(size_t)(d0 + r) * SEQ + s0 + c0 + 8] = w1;
  } else {
    // K convert: 512 blocks x 256 threads x 8 elems
    const int base = (b - 256) * 2048 + tid * 8;
    float4 a = *(const float4*)&K[base];
    float4 c = *(const float4*)&K[base + 4];
    bf16x8 f;
    f[0] = (bf16_t)a.x; f[1] = (bf16_t)a.y; f[2] = (bf16_t)a.z; f[3] = (bf16_t)a.w;
    f[4] = (bf16_t)c.x; f[5] = (bf16_t)c.y; f[6] = (bf16_t)c.z; f[7] = (bf16_t)c.w;
    *(bf16x8*)&Kb[base] = f;
  }
}

// ---------------- main flash-attention kernel ----------------
// S^T = K * Q^T (exp'd scores land in PV-A layout); 8 waves: group g = w>>2
// owns key-half g of each 64-key tile; double-buffered LDS, 1 barrier/iter.
__global__ __launch_bounds__(THREADS, 4) void fattn_kernel(
    const float* __restrict__ Q, const bf16_t* __restrict__ Kb,
    const bf16_t* __restrict__ VT, float* __restrict__ Opart,
    float* __restrict__ Lpart, int kshift, int nit) {
  __shared__ __align__(16) char smem[SMEM_BYTES];
  bf16_t (*kts)[BN][KTP] = (bf16_t(*)[BN][KTP])smem;           // 2 x 64 x 130
  bf16_t (*vts)[HD][VTP] = (bf16_t(*)[HD][VTP])(smem + KT_BYTES); // 2 x 128 x 66

  const int tid = (int)threadIdx.x;
  const int lane = tid & 63;
  const int w = tid >> 6;         // wave 0..7
  const int qw = w & 3;           // q-tile: rows [32*qw, 32*qw+32)
  const int g = w >> 2;           // key-group: keys [32g, 32g+32) of each tile
  const int h = lane >> 5;        // half-wave
  const int n32 = lane & 31;

  const int qt = (int)blockIdx.x >> kshift;
  const int sp = (int)blockIdx.x & ((1 << kshift) - 1);
  const int qbase = qt * BM;
  const int kbase0 = sp * (nit * BN);

  const float SC2 = 0.08838834764831845f * 1.4426950408889634f; // (1/sqrt(128))*log2e

  // staging coords (512 threads: 2 b128 chunks each for kt and vt)
  const int kr0 = tid >> 4;            // 0..31 (j adds 32)
  const int kc8 = (tid & 15) * 8;
  const int vd0 = tid >> 3;            // 0..63 (j adds 64)
  const int vc8 = (tid & 7) * 8;

  // Q B-frags (n = lane&31 = q-row, k = h*8+j), pre-scaled by SC2
  bf16x8 qf[8];
  {
    const float* qp = Q + (size_t)(qbase + qw * 32 + n32) * HD + h * 8;
#pragma unroll
    for (int kk = 0; kk < 8; ++kk) {
      float4 a = *(const float4*)(qp + kk * 16);
      float4 b = *(const float4*)(qp + kk * 16 + 4);
      bf16x8 f;
      f[0] = (bf16_t)(a.x * SC2); f[1] = (bf16_t)(a.y * SC2);
      f[2] = (bf16_t)(a.z * SC2); f[3] = (bf16_t)(a.w * SC2);
      f[4] = (bf16_t)(b.x * SC2); f[5] = (bf16_t)(b.y * SC2);
      f[6] = (bf16_t)(b.z * SC2); f[7] = (bf16_t)(b.w * SC2);
      qf[kk] = f;
    }
  }

  f32x16 o_acc[4];
#pragma unroll
  for (int i = 0; i < 4; ++i)
#pragma unroll
    for (int e = 0; e < 16; ++e) o_acc[i][e] = 0.f;
  float l_acc = 0.f;

  // ---- preload iter 0 into buffer 0 ----
  {
#pragma unroll
    for (int j = 0; j < 2; ++j) {
      bf16x8 kr = *(const bf16x8*)&Kb[(size_t)(kbase0 + kr0 + 32 * j) * HD + kc8];
      *(bf16x8*)&kts[0][kr0 + 32 * j][kc8] = kr;
    }
#pragma unroll
    for (int j = 0; j < 2; ++j) {
      bf16x8 vr = *(const bf16x8*)&VT[(size_t)(vd0 + 64 * j) * SEQ + kbase0 + vc8];
      *(bf16x8*)&vts[0][vd0 + 64 * j][vc8] = vr;
    }
  }
  __syncthreads();

  for (int it = 0; it < nit; ++it) {
    const int cur = it & 1;
    const int nxt = cur ^ 1;
    const int nk = (it + 1 < nit) ? kbase0 + (it + 1) * BN : kbase0;
    // prefetch next tile into regs (in flight across the compute section)
    bf16x8 kreg[2], vreg[2];
#pragma unroll
    for (int j = 0; j < 2; ++j)
      kreg[j] = *(const bf16x8*)&Kb[(size_t)(nk + kr0 + 32 * j) * HD + kc8];
#pragma unroll
    for (int j = 0; j < 2; ++j)
      vreg[j] = *(const bf16x8*)&VT[(size_t)(vd0 + 64 * j) * SEQ + nk + vc8];

    // ---- S^T(group g) = K_g Q^T : one 32(key) x 32(q) tile, K-dim = 128 ----
    f32x16 sacc;
#pragma unroll
    for (int e = 0; e < 16; ++e) sacc[e] = 0.f;
#pragma unroll
    for (int kk = 0; kk < 8; ++kk) {
      bf16x8 af = *(const bf16x8*)&kts[cur][g * 32 + n32][kk * 16 + h * 8];
      sacc = __builtin_amdgcn_mfma_f32_32x32x16_bf16(af, qf[kk], sacc, 0, 0, 0);
    }

    // ---- exp -> pack bf16 -> half-wave exchange -> PV over this group's keys ----
    // sacc[r] = S^T[key = g*32 + (r&3)+8*(r>>2)+4h][q = n32]  (pre-scaled)
    float pf[16];
#pragma unroll
    for (int r = 0; r < 16; ++r) pf[r] = exp2_fast(sacc[r]);
#pragma unroll
    for (int r = 0; r < 16; ++r) l_acc += pf[r];
    unsigned int pk[8];
#pragma unroll
    for (int gg = 0; gg < 4; ++gg) {
      bf16x2 p0; p0[0] = (bf16_t)pf[4 * gg + 0]; p0[1] = (bf16_t)pf[4 * gg + 1];
      bf16x2 p1; p1[0] = (bf16_t)pf[4 * gg + 2]; p1[1] = (bf16_t)pf[4 * gg + 3];
      pk[2 * gg + 0] = __builtin_bit_cast(unsigned int, p0);
      pk[2 * gg + 1] = __builtin_bit_cast(unsigned int, p1);
    }
#pragma unroll
    for (int kk2 = 0; kk2 < 2; ++kk2) {
      const unsigned int sA = pk[4 * kk2 + 0], sB = pk[4 * kk2 + 1];
      const unsigned int sC = pk[4 * kk2 + 2], sD = pk[4 * kk2 + 3];
      unsigned int s0 = h ? sA : sC, s1 = h ? sB : sD;
      unsigned int r0 = __shfl_xor(s0, 32);
      unsigned int r1 = __shfl_xor(s1, 32);
      unsigned int o0 = h ? sC : sA, o1 = h ? sD : sB;
      u32x4 fv;
      fv[0] = h ? r0 : o0; fv[1] = h ? r1 : o1;
      fv[2] = h ? o0 : r0; fv[3] = h ? o1 : r1;
      bf16x8 pa = __builtin_bit_cast(bf16x8, fv);
#pragma unroll
      for (int ot = 0; ot < 4; ++ot) {
        bf16x8 vb = *(const bf16x8*)&vts[cur][ot * 32 + n32][g * 32 + kk2 * 16 + h * 8];
        o_acc[ot] = __builtin_amdgcn_mfma_f32_32x32x16_bf16(pa, vb, o_acc[ot], 0, 0, 0);
      }
    }

    // ---- drain prefetch into the other buffer, single barrier ----
#pragma unroll
    for (int j = 0; j < 2; ++j) *(bf16x8*)&kts[nxt][kr0 + 32 * j][kc8] = kreg[j];
#pragma unroll
    for (int j = 0; j < 2; ++j) *(bf16x8*)&vts[nxt][vd0 + 64 * j][vc8] = vreg[j];
    __syncthreads();
  }

  // ---- epilogue: combine key-groups via LDS (staging smem is dead now) ----
  float* osum = (float*)smem;                 // [128][128] f32 = 64 KB
  float* lsum = (float*)(smem + 65536);       // [128] f32
  if (g == 1) {
#pragma unroll
    for (int ot = 0; ot < 4; ++ot)
#pragma unroll
      for (int reg = 0; reg < 16; ++reg) {
        const int row = (reg & 3) + 8 * (reg >> 2) + 4 * h;
        osum[(qw * 32 + row) * HD + ot * 32 + n32] = o_acc[ot][reg];
      }
    float l = l_acc + __shfl_xor(l_acc, 32);
    if (lane < 32) lsum[qw * 32 + n32] = l;
  }
  __syncthreads();
  if (g == 0) {
    float* op = Opart + ((size_t)sp * SEQ + qbase + qw * 32) * HD;
#pragma unroll
    for (int ot = 0; ot < 4; ++ot)
#pragma unroll
      for (int reg = 0; reg < 16; ++reg) {
        const int row = (reg & 3) + 8 * (reg >> 2) + 4 * h;
        op[row * HD + ot * 32 + n32] =
            o_acc[ot][reg] + osum[(qw * 32 + row) * HD + ot * 32 + n32];
      }
    float l = l_acc + __shfl_xor(l_acc, 32);
    if (lane < 32)
      Lpart[(size_t)sp * SEQ + qbase + qw * 32 + n32] = l + lsum[qw * 32 + n32];
  }
}

// ---------------- combine: out = sum_s O_s / sum_s l_s ----------------
__global__ __launch_bounds__(256) void combine_kernel(const float* __restrict__ Opart,
                                                      const float* __restrict__ Lpart,
                                                      float* __restrict__ out, int ksplit) {
  const int tid = (int)threadIdx.x;
  const int row = (int)blockIdx.x * 8 + (tid >> 5);
  const int c0 = (tid & 31) * 4;
  float lsum = 0.f;
  for (int s = 0; s < ksplit; ++s) lsum += Lpart[(size_t)s * SEQ + row];
  f32x4 acc;
#pragma unroll
  for (int e = 0; e < 4; ++e) acc[e] = 0.f;
  for (int s = 0; s < ksplit; ++s) {
    f32x4 o = *(const f32x4*)&Opart[((size_t)s * SEQ + row) * HD + c0];
#pragma unroll
    for (int e = 0; e < 4; ++e) acc[e] += o[e];
  }
  const float inv = 1.0f / lsum;
  f32x4 res;
#pragma unroll
  for (int e = 0; e < 4; ++e) res[e] = acc[e] * inv;
  *(f32x4*)&out[(size_t)row * HD + c0] = res;
}

extern "C" void kernel_launch(void* const* d_in, const int* in_sizes, int n_in,
                              void* d_out, int out_size, void* d_ws, size_t ws_size,
                              hipStream_t stream) {
  const float* Q = (const float*)d_in[0];
  const float* K = (const float*)d_in[1];
  const float* V = (const float*)d_in[2];
  float* out = (float*)d_out;

  int ksplit = 8, kshift = 3;
  while (ksplit > 1) {
    size_t need = (size_t)ksplit * SEQ * HD * 4
                + (size_t)ksplit * SEQ * 4
                + (size_t)SEQ * HD * 2 * 2;
    if (need <= ws_size) break;
    ksplit >>= 1; kshift--;
  }

  char* ws = (char*)d_ws;
  float* Opart = (float*)ws;
  float* Lpart = (float*)(ws + (size_t)ksplit * SEQ * HD * 4);
  bf16_t* Kb = (bf16_t*)(ws + (size_t)ksplit * SEQ * HD * 4 + (size_t)ksplit * SEQ * 4);
  bf16_t* VT = Kb + (size_t)SEQ * HD;

  const int nit = SEQ / (ksplit * BN);

  prep_kernel<<<768, 256, 0, stream>>>(K, V, Kb, VT);
  fattn_kernel<<<NQT * ksplit, THREADS, 0, stream>>>(Q, Kb, VT, Opart, Lpart, kshift, nit);
  combine_kernel<<<SEQ / 8, 256, 0, stream>>>(Opart, Lpart, out, ksplit);
}

// Round 5
// 137.370 us; speedup vs baseline: 1.6339x; 1.6339x over previous
//
#include <hip/hip_runtime.h>
#include <hip/hip_bf16.h>

#define SEQ 8192
#define HD 128
#define BM 128
#define BN 64
#define NQT (SEQ / BM)   // 64
#define THREADS 512

typedef __bf16 bf16_t;
typedef __bf16 bf16x2 __attribute__((ext_vector_type(2)));
typedef __bf16 bf16x8 __attribute__((ext_vector_type(8)));
typedef float f32x4 __attribute__((ext_vector_type(4)));
typedef float f32x16 __attribute__((ext_vector_type(16)));
typedef unsigned int u32x4 __attribute__((ext_vector_type(4)));

#if __has_builtin(__builtin_amdgcn_exp2f)
__device__ inline float exp2_fast(float x) { return __builtin_amdgcn_exp2f(x); }
#else
__device__ inline float exp2_fast(float x) { return exp2f(x); }
#endif

// async global->LDS DMA, 16 B per lane; lds dest must be wave-uniform base
__device__ inline void load_lds16(const void* g, void* l) {
  __builtin_amdgcn_global_load_lds(
      (const __attribute__((address_space(1))) void*)g,
      (__attribute__((address_space(3))) void*)l, 16, 0, 0);
}

// ---------------- prep: K -> bf16 swizzled, V -> bf16 transposed swizzled ----
// Kb layout: row r, 16-byte chunk c holds K[r][8*(c XOR (r&15)) .. +8]
// VT layout: row d, within each 64-key group, chunk c holds VT[d][g*64 + 8*(c XOR (d&7)) ..]
__global__ __launch_bounds__(256) void prep_kernel(const float* __restrict__ K,
                                                   const float* __restrict__ V,
                                                   bf16_t* __restrict__ Kb,
                                                   bf16_t* __restrict__ VT) {
  const int b = (int)blockIdx.x;
  const int tid = (int)threadIdx.x;
  if (b < 256) {
    // V^T tile: 64 (s) x 64 (d)
    __shared__ float tile[64][65];
    const int s0 = (b & 127) * 64;
    const int d0 = (b >> 7) * 64;
    const int r = tid >> 2;          // 0..63
    const int c0 = (tid & 3) * 16;   // 0,16,32,48
#pragma unroll
    for (int j4 = 0; j4 < 4; ++j4) {
      float4 x = *(const float4*)&V[(size_t)(s0 + r) * HD + d0 + c0 + j4 * 4];
      tile[r][c0 + j4 * 4 + 0] = x.x;
      tile[r][c0 + j4 * 4 + 1] = x.y;
      tile[r][c0 + j4 * 4 + 2] = x.z;
      tile[r][c0 + j4 * 4 + 3] = x.w;
    }
    __syncthreads();
    bf16x8 w0, w1;
#pragma unroll
    for (int j = 0; j < 8; ++j) w0[j] = (bf16_t)tile[c0 + j][r];
#pragma unroll
    for (int j = 0; j < 8; ++j) w1[j] = (bf16_t)tile[c0 + 8 + j][r];
    const int d = d0 + r;
    const int cch = c0 >> 3;                 // 0,2,4,6 (chunk within 8-chunk group)
    const int j0 = (cch) ^ (d & 7);
    const int j1 = (cch + 1) ^ (d & 7);
    *(bf16x8*)&VT[(size_t)d * SEQ + s0 + j0 * 8] = w0;
    *(bf16x8*)&VT[(size_t)d * SEQ + s0 + j1 * 8] = w1;
  } else {
    // K convert: 512 blocks x 256 threads x 8 elems (one 16B chunk each)
    const int base = (b - 256) * 2048 + tid * 8;
    const int row = base >> 7;
    const int c = (base >> 3) & 15;
    float4 a = *(const float4*)&K[base];
    float4 cc = *(const float4*)&K[base + 4];
    bf16x8 f;
    f[0] = (bf16_t)a.x; f[1] = (bf16_t)a.y; f[2] = (bf16_t)a.z; f[3] = (bf16_t)a.w;
    f[4] = (bf16_t)cc.x; f[5] = (bf16_t)cc.y; f[6] = (bf16_t)cc.z; f[7] = (bf16_t)cc.w;
    *(bf16x8*)&Kb[(size_t)row * HD + (c ^ (row & 15)) * 8] = f;
  }
}

// ---------------- main flash-attention kernel ----------------
// S^T = K * Q^T; 8 waves: (qw = w&3) q-tile, (g = w>>2) key-half of each 64-key
// tile. Double-buffered unpadded LDS fed by global_load_lds DMA (swizzled
// source layout -> conflict-free reads). One __syncthreads per iter.
__global__ __launch_bounds__(THREADS, 4) void fattn_kernel(
    const float* __restrict__ Q, const bf16_t* __restrict__ Kb,
    const bf16_t* __restrict__ VT, float* __restrict__ Opart,
    float* __restrict__ Lpart, int kshift, int nit) {
  __shared__ __align__(16) bf16_t kt2[2][BN][HD];   // 2 x 16 KB (chunk-swizzled)
  __shared__ __align__(16) bf16_t vt2[2][HD][BN];   // 2 x 16 KB (chunk-swizzled)
  __shared__ float lsumbuf[BM];

  const int tid = (int)threadIdx.x;
  const int lane = tid & 63;
  const int w = tid >> 6;         // wave 0..7
  const int qw = w & 3;           // q-tile: rows [32*qw, +32)
  const int g = w >> 2;           // key-half: keys [32g, +32) of each tile
  const int h = lane >> 5;
  const int n32 = lane & 31;

  const int qt = (int)blockIdx.x >> kshift;
  const int sp = (int)blockIdx.x & ((1 << kshift) - 1);
  const int qbase = qt * BM;
  const int kbase0 = sp * (nit * BN);

  const float SC2 = 0.08838834764831845f * 1.4426950408889634f; // (1/sqrt(128))*log2e

  // Q B-frags (n = n32 = q-row, k = h*8 + j), pre-scaled by SC2
  bf16x8 qf[8];
  {
    const float* qp = Q + (size_t)(qbase + qw * 32 + n32) * HD + h * 8;
#pragma unroll
    for (int kk = 0; kk < 8; ++kk) {
      float4 a = *(const float4*)(qp + kk * 16);
      float4 b = *(const float4*)(qp + kk * 16 + 4);
      bf16x8 f;
      f[0] = (bf16_t)(a.x * SC2); f[1] = (bf16_t)(a.y * SC2);
      f[2] = (bf16_t)(a.z * SC2); f[3] = (bf16_t)(a.w * SC2);
      f[4] = (bf16_t)(b.x * SC2); f[5] = (bf16_t)(b.y * SC2);
      f[6] = (bf16_t)(b.z * SC2); f[7] = (bf16_t)(b.w * SC2);
      qf[kk] = f;
    }
  }

  f32x16 o_acc[4];
#pragma unroll
  for (int i = 0; i < 4; ++i)
#pragma unroll
    for (int e = 0; e < 16; ++e) o_acc[i][e] = 0.f;
  float l_acc = 0.f;

  // per-lane DMA source pieces (lds dest is wave-uniform; HW adds lane*16)
  // kt: linear 1 KB per (wave, t): src elem off = kbase*HD + (w*2+t)*512 + lane*8
  // vt: lane covers d = (w*2+t)*8 + (lane>>3), chunk = lane&7
  const int vd_lo = (lane >> 3);
  const int vc8 = (lane & 7) * 8;

  // ---- preload tile 0 into buffer 0 ----
#pragma unroll
  for (int t = 0; t < 2; ++t) {
    load_lds16(Kb + (size_t)kbase0 * HD + (w * 2 + t) * 512 + lane * 8,
               (char*)&kt2[0][0][0] + (w * 2 + t) * 1024);
    load_lds16(VT + (size_t)((w * 2 + t) * 8 + vd_lo) * SEQ + kbase0 + vc8,
               (char*)&vt2[0][0][0] + (w * 2 + t) * 1024);
  }
  __syncthreads();

  const int arow = g * 32 + n32;
  const int aswz = n32 & 15;
  const int vswz = n32 & 7;

  for (int it = 0; it < nit; ++it) {
    const int cur = it & 1;
    const int nxt = cur ^ 1;
    const int nk = kbase0 + ((it + 1 < nit) ? (it + 1) * BN : 0);
    // issue next-tile DMA into nxt buffers (in flight across entire compute)
#pragma unroll
    for (int t = 0; t < 2; ++t) {
      load_lds16(Kb + (size_t)nk * HD + (w * 2 + t) * 512 + lane * 8,
                 (char*)&kt2[nxt][0][0] + (w * 2 + t) * 1024);
      load_lds16(VT + (size_t)((w * 2 + t) * 8 + vd_lo) * SEQ + nk + vc8,
                 (char*)&vt2[nxt][0][0] + (w * 2 + t) * 1024);
    }

    // ---- S^T(half g) = K_g Q^T : 32(key) x 32(q), K-dim = 128 ----
    f32x16 sacc;
#pragma unroll
    for (int e = 0; e < 16; ++e) sacc[e] = 0.f;
#pragma unroll
    for (int kk = 0; kk < 8; ++kk) {
      bf16x8 af = *(const bf16x8*)&kt2[cur][arow][((2 * kk + h) ^ aswz) * 8];
      sacc = __builtin_amdgcn_mfma_f32_32x32x16_bf16(af, qf[kk], sacc, 0, 0, 0);
    }

    // ---- exp -> pack -> half-wave exchange -> PV, per 16-key sub-frag ----
    // sacc[r] = S^T[key = g*32 + (r&3)+8*(r>>2)+4h][q = n32]
#pragma unroll
    for (int kk2 = 0; kk2 < 2; ++kk2) {
      float pf[8];
#pragma unroll
      for (int j = 0; j < 8; ++j) pf[j] = exp2_fast(sacc[8 * kk2 + j]);
#pragma unroll
      for (int j = 0; j < 8; ++j) l_acc += pf[j];
      bf16x2 p0, p1, p2, p3;
      p0[0] = (bf16_t)pf[0]; p0[1] = (bf16_t)pf[1];
      p1[0] = (bf16_t)pf[2]; p1[1] = (bf16_t)pf[3];
      p2[0] = (bf16_t)pf[4]; p2[1] = (bf16_t)pf[5];
      p3[0] = (bf16_t)pf[6]; p3[1] = (bf16_t)pf[7];
      const unsigned int sA = __builtin_bit_cast(unsigned int, p0);
      const unsigned int sB = __builtin_bit_cast(unsigned int, p1);
      const unsigned int sC = __builtin_bit_cast(unsigned int, p2);
      const unsigned int sD = __builtin_bit_cast(unsigned int, p3);
      unsigned int s0 = h ? sA : sC, s1 = h ? sB : sD;
      unsigned int r0 = __shfl_xor(s0, 32);
      unsigned int r1 = __shfl_xor(s1, 32);
      unsigned int o0 = h ? sC : sA, o1 = h ? sD : sB;
      u32x4 fv;
      fv[0] = h ? r0 : o0; fv[1] = h ? r1 : o1;
      fv[2] = h ? o0 : r0; fv[3] = h ? o1 : r1;
      bf16x8 pa = __builtin_bit_cast(bf16x8, fv);
#pragma unroll
      for (int ot = 0; ot < 4; ++ot) {
        bf16x8 vb = *(const bf16x8*)&vt2[cur][ot * 32 + n32]
                                       [((4 * g + 2 * kk2 + h) ^ vswz) * 8];
        o_acc[ot] = __builtin_amdgcn_mfma_f32_32x32x16_bf16(pa, vb, o_acc[ot], 0, 0, 0);
      }
    }

    __syncthreads();   // drains DMA (vmcnt) + LDS reads; swaps buffers
  }

  // ---- epilogue: combine key-halves via LDS (tile smem is dead now) ----
  float* osum = (float*)&kt2[0][0][0];        // 64 KB = 128x128 f32
  if (g == 1) {
#pragma unroll
    for (int ot = 0; ot < 4; ++ot)
#pragma unroll
      for (int reg = 0; reg < 16; ++reg) {
        const int row = (reg & 3) + 8 * (reg >> 2) + 4 * h;
        osum[(qw * 32 + row) * HD + ot * 32 + n32] = o_acc[ot][reg];
      }
    float l = l_acc + __shfl_xor(l_acc, 32);
    if (lane < 32) lsumbuf[qw * 32 + n32] = l;
  }
  __syncthreads();
  if (g == 0) {
    float* op = Opart + ((size_t)sp * SEQ + qbase + qw * 32) * HD;
#pragma unroll
    for (int ot = 0; ot < 4; ++ot)
#pragma unroll
      for (int reg = 0; reg < 16; ++reg) {
        const int row = (reg & 3) + 8 * (reg >> 2) + 4 * h;
        op[row * HD + ot * 32 + n32] =
            o_acc[ot][reg] + osum[(qw * 32 + row) * HD + ot * 32 + n32];
      }
    float l = l_acc + __shfl_xor(l_acc, 32);
    if (lane < 32)
      Lpart[(size_t)sp * SEQ + qbase + qw * 32 + n32] = l + lsumbuf[qw * 32 + n32];
  }
}

// ---------------- combine: out = sum_s O_s / sum_s l_s ----------------
__global__ __launch_bounds__(256) void combine_kernel(const float* __restrict__ Opart,
                                                      const float* __restrict__ Lpart,
                                                      float* __restrict__ out, int ksplit) {
  const int tid = (int)threadIdx.x;
  const int row = (int)blockIdx.x * 8 + (tid >> 5);
  const int c0 = (tid & 31) * 4;
  float lsum = 0.f;
  for (int s = 0; s < ksplit; ++s) lsum += Lpart[(size_t)s * SEQ + row];
  f32x4 acc;
#pragma unroll
  for (int e = 0; e < 4; ++e) acc[e] = 0.f;
  for (int s = 0; s < ksplit; ++s) {
    f32x4 o = *(const f32x4*)&Opart[((size_t)s * SEQ + row) * HD + c0];
#pragma unroll
    for (int e = 0; e < 4; ++e) acc[e] += o[e];
  }
  const float inv = 1.0f / lsum;
  f32x4 res;
#pragma unroll
  for (int e = 0; e < 4; ++e) res[e] = acc[e] * inv;
  *(f32x4*)&out[(size_t)row * HD + c0] = res;
}

extern "C" void kernel_launch(void* const* d_in, const int* in_sizes, int n_in,
                              void* d_out, int out_size, void* d_ws, size_t ws_size,
                              hipStream_t stream) {
  const float* Q = (const float*)d_in[0];
  const float* K = (const float*)d_in[1];
  const float* V = (const float*)d_in[2];
  float* out = (float*)d_out;

  int ksplit = 8, kshift = 3;
  while (ksplit > 1) {
    size_t need = (size_t)ksplit * SEQ * HD * 4
                + (size_t)ksplit * SEQ * 4
                + (size_t)SEQ * HD * 2 * 2;
    if (need <= ws_size) break;
    ksplit >>= 1; kshift--;
  }

  char* ws = (char*)d_ws;
  float* Opart = (float*)ws;
  float* Lpart = (float*)(ws + (size_t)ksplit * SEQ * HD * 4);
  bf16_t* Kb = (bf16_t*)(ws + (size_t)ksplit * SEQ * HD * 4 + (size_t)ksplit * SEQ * 4);
  bf16_t* VT = Kb + (size_t)SEQ * HD;

  const int nit = SEQ / (ksplit * BN);

  prep_kernel<<<768, 256, 0, stream>>>(K, V, Kb, VT);
  fattn_kernel<<<NQT * ksplit, THREADS, 0, stream>>>(Q, Kb, VT, Opart, Lpart, kshift, nit);
  combine_kernel<<<SEQ / 8, 256, 0, stream>>>(Opart, Lpart, out, ksplit);
}

// Round 6
// 116.004 us; speedup vs baseline: 1.9348x; 1.1842x over previous
//
#include <hip/hip_runtime.h>
#include <hip/hip_bf16.h>

#define SEQ 8192
#define HD 128
#define BM 128
#define BN 64
#define NQT (SEQ / BM)   // 64
#define THREADS 512

typedef __bf16 bf16_t;
typedef __bf16 bf16x2 __attribute__((ext_vector_type(2)));
typedef __bf16 bf16x8 __attribute__((ext_vector_type(8)));
typedef float f32x4 __attribute__((ext_vector_type(4)));
typedef float f32x16 __attribute__((ext_vector_type(16)));
typedef unsigned int u32x4 __attribute__((ext_vector_type(4)));

#if __has_builtin(__builtin_amdgcn_exp2f)
__device__ inline float exp2_fast(float x) { return __builtin_amdgcn_exp2f(x); }
#else
__device__ inline float exp2_fast(float x) { return exp2f(x); }
#endif

// async global->LDS DMA, 16 B per lane; lds dest wave-uniform, HW adds lane*16
__device__ inline void load_lds16(const void* g, void* l) {
  __builtin_amdgcn_global_load_lds(
      (const __attribute__((address_space(1))) void*)g,
      (__attribute__((address_space(3))) void*)l, 16, 0, 0);
}

// ---------------- prep ----------------
// Kb blocked: [tile T][d-chunk c 0..15][key r 0..63][8]  = K[T*64+r][c*8+j]
// VT blocked: [tile T][key-chunk kc 0..7][d 0..127][8]   = V[T*64+kc*8+j][d]
__global__ __launch_bounds__(256) void prep_kernel(const float* __restrict__ K,
                                                   const float* __restrict__ V,
                                                   bf16_t* __restrict__ Kb,
                                                   bf16_t* __restrict__ VT) {
  const int b = (int)blockIdx.x;
  const int tid = (int)threadIdx.x;
  if (b < 256) {
    // V tile: 64 keys x 64 d, staged f32 in LDS (coalesced reads)
    __shared__ float tile[64][65];
    const int T = b & 127;
    const int d0 = (b >> 7) * 64;
    const int s0 = T * 64;
    const int r = tid >> 2;          // 0..63 (key)
    const int c0 = (tid & 3) * 16;   // d offset
#pragma unroll
    for (int j4 = 0; j4 < 4; ++j4) {
      float4 x = *(const float4*)&V[(size_t)(s0 + r) * HD + d0 + c0 + j4 * 4];
      tile[r][c0 + j4 * 4 + 0] = x.x;
      tile[r][c0 + j4 * 4 + 1] = x.y;
      tile[r][c0 + j4 * 4 + 2] = x.z;
      tile[r][c0 + j4 * 4 + 3] = x.w;
    }
    __syncthreads();
    const int d_l = tid & 63;
    const int kc0 = (tid >> 6) * 2;  // 0,2,4,6
#pragma unroll
    for (int k2 = 0; k2 < 2; ++k2) {
      const int kc = kc0 + k2;
      bf16x8 wv;
#pragma unroll
      for (int j = 0; j < 8; ++j) wv[j] = (bf16_t)tile[kc * 8 + j][d_l];
      *(bf16x8*)&VT[((size_t)(T * 8 + kc) * 128 + d0 + d_l) * 8] = wv;
    }
  } else {
    // K convert: one 16B chunk per thread
    const int base = (b - 256) * 2048 + tid * 8;   // flat over 8192*128
    const int row = base >> 7;
    const int c = (base >> 3) & 15;
    const int T = row >> 6;
    const int r = row & 63;
    float4 a = *(const float4*)&K[base];
    float4 cc = *(const float4*)&K[base + 4];
    bf16x8 f;
    f[0] = (bf16_t)a.x; f[1] = (bf16_t)a.y; f[2] = (bf16_t)a.z; f[3] = (bf16_t)a.w;
    f[4] = (bf16_t)cc.x; f[5] = (bf16_t)cc.y; f[6] = (bf16_t)cc.z; f[7] = (bf16_t)cc.w;
    *(bf16x8*)&Kb[((size_t)(T * 16 + c) * 64 + r) * 8] = f;
  }
}

// ---------------- main flash-attention kernel ----------------
// 8 waves: qw = w&3 (32 q-rows), g = w>>2. Wave (qw,g): QK^T for key-half g
// (S^T layout), exp, write A-layout P chunks to LDS; after barrier, PV over
// ALL 64 keys restricted to d-half g -> o_acc is 32 regs. All LDS accesses
// lane-linear (conflict-free); staging via global_load_lds DMA, double-buffered.
__global__ __launch_bounds__(THREADS, 4) void fattn_kernel(
    const float* __restrict__ Q, const bf16_t* __restrict__ Kb,
    const bf16_t* __restrict__ VT, float* __restrict__ Opart,
    float* __restrict__ Lpart, int kshift, int nit) {
  __shared__ __align__(16) bf16_t kt2[2][16][64][8];  // 32 KB [buf][d-chunk][key][8]
  __shared__ __align__(16) bf16_t vt2[2][8][128][8];  // 32 KB [buf][key-chunk][d][8]
  __shared__ __align__(16) char pbuf[4][4][64][16];   // 16 KB [qw][key-chunk16][lane][16B]

  const int tid = (int)threadIdx.x;
  const int lane = tid & 63;
  const int w = tid >> 6;
  const int qw = w & 3;
  const int g = w >> 2;
  const int h = lane >> 5;
  const int n32 = lane & 31;

  const int qt = (int)blockIdx.x >> kshift;
  const int sp = (int)blockIdx.x & ((1 << kshift) - 1);
  const int qbase = qt * BM;
  const int tile0 = sp * nit;          // first 64-key tile index

  const float SC2 = 0.08838834764831845f * 1.4426950408889634f; // (1/sqrt(128))*log2e

  // Q B-frags (n = n32 = q-row, k-dim = d), pre-scaled
  bf16x8 qf[8];
  {
    const float* qp = Q + (size_t)(qbase + qw * 32 + n32) * HD + h * 8;
#pragma unroll
    for (int kk = 0; kk < 8; ++kk) {
      float4 a = *(const float4*)(qp + kk * 16);
      float4 b = *(const float4*)(qp + kk * 16 + 4);
      bf16x8 f;
      f[0] = (bf16_t)(a.x * SC2); f[1] = (bf16_t)(a.y * SC2);
      f[2] = (bf16_t)(a.z * SC2); f[3] = (bf16_t)(a.w * SC2);
      f[4] = (bf16_t)(b.x * SC2); f[5] = (bf16_t)(b.y * SC2);
      f[6] = (bf16_t)(b.z * SC2); f[7] = (bf16_t)(b.w * SC2);
      qf[kk] = f;
    }
  }

  f32x16 o_acc[2];
#pragma unroll
  for (int i = 0; i < 2; ++i)
#pragma unroll
    for (int e = 0; e < 16; ++e) o_acc[i][e] = 0.f;
  float l_acc = 0.f;

  const int rr0 = w * 2;   // DMA region indices rr0, rr0+1

  // ---- preload tile0 into buffer 0 ----
#pragma unroll
  for (int t = 0; t < 2; ++t) {
    const int rr = rr0 + t;
    load_lds16(Kb + ((size_t)(tile0 * 16 + rr) * 64 + lane) * 8,
               (char*)&kt2[0][0][0][0] + rr * 1024);
    load_lds16(VT + ((size_t)(tile0 * 8 + (rr >> 1)) * 128 + (rr & 1) * 64 + lane) * 8,
               (char*)&vt2[0][0][0][0] + rr * 1024);
  }
  __syncthreads();

  for (int it = 0; it < nit; ++it) {
    const int cur = it & 1;
    const int nxt = cur ^ 1;
    const int ntile = tile0 + ((it + 1 < nit) ? it + 1 : 0);
    // issue next-tile DMA (in flight across the whole iteration)
#pragma unroll
    for (int t = 0; t < 2; ++t) {
      const int rr = rr0 + t;
      load_lds16(Kb + ((size_t)(ntile * 16 + rr) * 64 + lane) * 8,
                 (char*)&kt2[nxt][0][0][0] + rr * 1024);
      load_lds16(VT + ((size_t)(ntile * 8 + (rr >> 1)) * 128 + (rr & 1) * 64 + lane) * 8,
                 (char*)&vt2[nxt][0][0][0] + rr * 1024);
    }

    // ---- S^T(key-half g) = K_g Q^T : 32 x 32, K-dim 128 ----
    f32x16 sacc;
#pragma unroll
    for (int e = 0; e < 16; ++e) sacc[e] = 0.f;
#pragma unroll
    for (int kk = 0; kk < 8; ++kk) {
      bf16x8 af = *(const bf16x8*)&kt2[cur][2 * kk + h][g * 32 + n32][0];
      sacc = __builtin_amdgcn_mfma_f32_32x32x16_bf16(af, qf[kk], sacc, 0, 0, 0);
    }

    // ---- exp -> pack -> half-wave exchange -> write A-layout P chunks ----
    // sacc[r] = S^T[key = g*32 + (r&3)+8*(r>>2)+4h][q = n32]
#pragma unroll
    for (int kk2 = 0; kk2 < 2; ++kk2) {
      float pf[8];
#pragma unroll
      for (int j = 0; j < 8; ++j) pf[j] = exp2_fast(sacc[8 * kk2 + j]);
#pragma unroll
      for (int j = 0; j < 8; ++j) l_acc += pf[j];
      bf16x2 p0, p1, p2, p3;
      p0[0] = (bf16_t)pf[0]; p0[1] = (bf16_t)pf[1];
      p1[0] = (bf16_t)pf[2]; p1[1] = (bf16_t)pf[3];
      p2[0] = (bf16_t)pf[4]; p2[1] = (bf16_t)pf[5];
      p3[0] = (bf16_t)pf[6]; p3[1] = (bf16_t)pf[7];
      const unsigned int sA = __builtin_bit_cast(unsigned int, p0);
      const unsigned int sB = __builtin_bit_cast(unsigned int, p1);
      const unsigned int sC = __builtin_bit_cast(unsigned int, p2);
      const unsigned int sD = __builtin_bit_cast(unsigned int, p3);
      unsigned int s0 = h ? sA : sC, s1 = h ? sB : sD;
      unsigned int r0 = __shfl_xor(s0, 32);
      unsigned int r1 = __shfl_xor(s1, 32);
      unsigned int o0 = h ? sC : sA, o1 = h ? sD : sB;
      u32x4 fv;
      fv[0] = h ? r0 : o0; fv[1] = h ? r1 : o1;
      fv[2] = h ? o0 : r0; fv[3] = h ? o1 : r1;
      *(u32x4*)&pbuf[qw][g * 2 + kk2][lane][0] = fv;   // lane-linear write
    }
    __syncthreads();   // P visible to sibling wave

    // ---- O(d-half g) += P(all 64 keys) V ----
#pragma unroll
    for (int C = 0; C < 4; ++C) {
      bf16x8 pa = *(const bf16x8*)&pbuf[qw][C][h * 32 + n32][0];
#pragma unroll
      for (int ot = 0; ot < 2; ++ot) {
        bf16x8 vb = *(const bf16x8*)&vt2[cur][C * 2 + h][g * 64 + ot * 32 + n32][0];
        o_acc[ot] = __builtin_amdgcn_mfma_f32_32x32x16_bf16(pa, vb, o_acc[ot], 0, 0, 0);
      }
    }

    __syncthreads();   // drains DMA (vmcnt) + pbuf/vt reads; buffer swap
  }

  // ---- epilogue: O block store (distinct q x d block per wave) + l combine ----
  {
    float* op = Opart + ((size_t)sp * SEQ + qbase + qw * 32) * HD + g * 64;
#pragma unroll
    for (int ot = 0; ot < 2; ++ot)
#pragma unroll
      for (int reg = 0; reg < 16; ++reg) {
        const int row = (reg & 3) + 8 * (reg >> 2) + 4 * h;
        op[row * HD + ot * 32 + n32] = o_acc[ot][reg];
      }
    float l = l_acc + __shfl_xor(l_acc, 32);   // this wave's 32 keys, per q
    float* lfb = (float*)pbuf;
    if (lane < 32) lfb[g * 128 + qw * 32 + n32] = l;
    __syncthreads();
    if (g == 0 && lane < 32)
      Lpart[(size_t)sp * SEQ + qbase + qw * 32 + n32] =
          l + lfb[128 + qw * 32 + n32];
  }
}

// ---------------- combine: out = sum_s O_s / sum_s l_s ----------------
__global__ __launch_bounds__(256) void combine_kernel(const float* __restrict__ Opart,
                                                      const float* __restrict__ Lpart,
                                                      float* __restrict__ out, int ksplit) {
  const int tid = (int)threadIdx.x;
  const int row = (int)blockIdx.x * 8 + (tid >> 5);
  const int c0 = (tid & 31) * 4;
  float lsum = 0.f;
  for (int s = 0; s < ksplit; ++s) lsum += Lpart[(size_t)s * SEQ + row];
  f32x4 acc;
#pragma unroll
  for (int e = 0; e < 4; ++e) acc[e] = 0.f;
  for (int s = 0; s < ksplit; ++s) {
    f32x4 o = *(const f32x4*)&Opart[((size_t)s * SEQ + row) * HD + c0];
#pragma unroll
    for (int e = 0; e < 4; ++e) acc[e] += o[e];
  }
  const float inv = 1.0f / lsum;
  f32x4 res;
#pragma unroll
  for (int e = 0; e < 4; ++e) res[e] = acc[e] * inv;
  *(f32x4*)&out[(size_t)row * HD + c0] = res;
}

extern "C" void kernel_launch(void* const* d_in, const int* in_sizes, int n_in,
                              void* d_out, int out_size, void* d_ws, size_t ws_size,
                              hipStream_t stream) {
  const float* Q = (const float*)d_in[0];
  const float* K = (const float*)d_in[1];
  const float* V = (const float*)d_in[2];
  float* out = (float*)d_out;

  int ksplit = 8, kshift = 3;
  while (ksplit > 1) {
    size_t need = (size_t)ksplit * SEQ * HD * 4
                + (size_t)ksplit * SEQ * 4
                + (size_t)SEQ * HD * 2 * 2;
    if (need <= ws_size) break;
    ksplit >>= 1; kshift--;
  }

  char* ws = (char*)d_ws;
  float* Opart = (float*)ws;
  float* Lpart = (float*)(ws + (size_t)ksplit * SEQ * HD * 4);
  bf16_t* Kb = (bf16_t*)(ws + (size_t)ksplit * SEQ * HD * 4 + (size_t)ksplit * SEQ * 4);
  bf16_t* VT = Kb + (size_t)SEQ * HD;

  const int nit = SEQ / (ksplit * BN);

  prep_kernel<<<768, 256, 0, stream>>>(K, V, Kb, VT);
  fattn_kernel<<<NQT * ksplit, THREADS, 0, stream>>>(Q, Kb, VT, Opart, Lpart, kshift, nit);
  combine_kernel<<<SEQ / 8, 256, 0, stream>>>(Opart, Lpart, out, ksplit);
}